// Round 5
// baseline (296.004 us; speedup 1.0000x reference)
//
#include <hip/hip_runtime.h>
#include <hip/hip_bf16.h>

constexpr int N  = 50000;
constexpr int E  = 800000;
constexpr int F0 = 128;
constexpr int H1 = 32;
constexpr int F1 = 256;
constexpr int F2 = 64;
constexpr int NB = (N + 255) / 256;        // 196 scan blocks
constexpr int NPAD = 782 * 64;             // 50048
constexpr int W1SZ = F0 * F1;              // 32768
constexpr int W2SZ = F1 * F2;              // 16384
constexpr float NEG_SLOPE = 0.2f;

typedef unsigned short u16;
typedef unsigned int   u32;
typedef __attribute__((ext_vector_type(8))) short bf16x8;
typedef __attribute__((ext_vector_type(4))) float f32x4;

__device__ __forceinline__ float leaky(float e) {
    return fmaxf(e, 0.f) + NEG_SLOPE * fminf(e, 0.f);
}
__device__ __forceinline__ float bf2f(u16 u) {
    u32 v = ((u32)u) << 16;
    return __builtin_bit_cast(float, v);
}
__device__ __forceinline__ u16 f2bf(float f) {
    u32 u = __builtin_bit_cast(u32, f);
    u += 0x7fffu + ((u >> 16) & 1u);
    return (u16)(u >> 16);
}
__device__ __forceinline__ u32 pack2(float a, float b) {
    return (u32)f2bf(a) | ((u32)f2bf(b) << 16);
}
__device__ __forceinline__ void up2(u32 v, float& lo, float& hi) {
    lo = __builtin_bit_cast(float, v << 16);
    hi = __builtin_bit_cast(float, v & 0xffff0000u);
}

// ---------------------------------------------------------------------------
// 0. edge_index dtype detect (int64 vs int32)
__global__ void k_detect(const unsigned long long* __restrict__ p, int* __restrict__ flag) {
    __shared__ int bad;
    if (threadIdx.x == 0) bad = 0;
    __syncthreads();
    unsigned long long v = p[threadIdx.x];
    if (v >= (unsigned long long)N) atomicOr(&bad, 1);
    __syncthreads();
    if (threadIdx.x == 0) *flag = bad ? 0 : 1;
}
__device__ __forceinline__ int load_idx(const void* ei, long long i, int is64) {
    return is64 ? (int)((const long long*)ei)[i] : ((const int*)ei)[i];
}

// ---------------------------------------------------------------------------
// 1. CSR build by dst
__global__ void k_count(const void* __restrict__ ei, const int* __restrict__ flag,
                        int* __restrict__ deg) {
    int e = blockIdx.x * blockDim.x + threadIdx.x;
    if (e >= E) return;
    int dst = load_idx(ei, (long long)E + e, *flag);
    atomicAdd(&deg[dst], 1);
}
__global__ __launch_bounds__(256) void k_bsum(const int* __restrict__ deg, int* __restrict__ bsum) {
    int b = blockIdx.x, t = threadIdx.x, i = b * 256 + t;
    int v = (i < N) ? deg[i] : 0;
#pragma unroll
    for (int o = 1; o < 64; o <<= 1) v += __shfl_xor(v, o, 64);
    __shared__ int sw[4];
    if ((t & 63) == 0) sw[t >> 6] = v;
    __syncthreads();
    if (t == 0) bsum[b] = sw[0] + sw[1] + sw[2] + sw[3];
}
__global__ __launch_bounds__(256) void k_bscan(int* __restrict__ bsum, int* __restrict__ rsN) {
    int t = threadIdx.x, lane = t & 63, wy = t >> 6;
    int v = (t < NB) ? bsum[t] : 0;
    int inc = v;
#pragma unroll
    for (int o = 1; o < 64; o <<= 1) { int u = __shfl_up(inc, o, 64); if (lane >= o) inc += u; }
    __shared__ int wtot[4];
    if (lane == 63) wtot[wy] = inc;
    __syncthreads();
    int offs = 0;
    for (int k = 0; k < wy; k++) offs += wtot[k];
    int excl = offs + inc - v;
    if (t < NB) bsum[t] = excl;
    if (t == NB - 1) *rsN = excl + v;
}
__global__ __launch_bounds__(256) void k_rs(const int* __restrict__ deg,
                                            const int* __restrict__ bsum, int* __restrict__ rs) {
    int b = blockIdx.x, t = threadIdx.x, i = b * 256 + t;
    int lane = t & 63, wy = t >> 6;
    int v = (i < N) ? deg[i] : 0;
    int inc = v;
#pragma unroll
    for (int o = 1; o < 64; o <<= 1) { int u = __shfl_up(inc, o, 64); if (lane >= o) inc += u; }
    __shared__ int wtot[4];
    if (lane == 63) wtot[wy] = inc;
    __syncthreads();
    int offs = bsum[b];
    for (int k = 0; k < wy; k++) offs += wtot[k];
    if (i < N) rs[i] = offs + inc - v;
}
// scatter: rs2 is a scratch copy of rs used as the fill cursor
__global__ void k_scatter(const void* __restrict__ ei, const int* __restrict__ flag,
                          int* __restrict__ rs2, int* __restrict__ csr) {
    int e = blockIdx.x * blockDim.x + threadIdx.x;
    if (e >= E) return;
    int is64 = *flag;
    int src = load_idx(ei, e, is64);
    int dst = load_idx(ei, (long long)E + e, is64);
    int pos = atomicAdd(&rs2[dst], 1);
    csr[pos] = src;
}

// ---------------------------------------------------------------------------
// 2. Prep weights: fp32 -> bf16, transposed [n][k], pre-swizzled (k ^= (n&7)<<3).
__global__ __launch_bounds__(256) void k_prepw(
        const float* __restrict__ W1, const float* __restrict__ W2,
        u16* __restrict__ w1t, u16* __restrict__ w2t) {
    int i = blockIdx.x * 256 + threadIdx.x;
    if (i < W1SZ) {
        int n = i >> 7, k = i & 127;
        w1t[(n << 7) + (k ^ ((n & 7) << 3))] = f2bf(W1[k * F1 + n]);
    } else if (i < W1SZ + W2SZ) {
        int j = i - W1SZ;
        int n = j >> 8, k = j & 255;
        w2t[(n << 8) + (k ^ ((n & 7) << 3))] = f2bf(W2[k * F2 + n]);
    }
}

// ---------------------------------------------------------------------------
// 3. GEMM1 (MFMA) + fused alpha1. Block 64 rows x 256 cols, 4 waves;
//    wave w owns cols w*64..w*64+63 = heads w*8..w*8+7 (8-lane shfl reduce).
__global__ __launch_bounds__(256) void k_gemm1(
        const float* __restrict__ x, const u16* __restrict__ w1t,
        const float* __restrict__ as1, const float* __restrict__ ad1,
        u16* __restrict__ h1b, float* __restrict__ asrc1, float* __restrict__ adst1) {
    __shared__ u16 As[64 * 128];   // 16KB, swizzled rows
    int r0 = blockIdx.x * 64;
    int t = threadIdx.x, w = t >> 6, l = t & 63;
    {   // stage: thread t -> row t>>2, 32 cols at (t&3)*32; fp32->bf16 inline
        int r = t >> 2, k0 = (t & 3) * 32, rr = r0 + r;
        int swz = (r & 7) << 3;
        float4 f[8];
        if (rr < N) {
            const float4* px = (const float4*)(x + (size_t)rr * F0 + k0);
#pragma unroll
            for (int j = 0; j < 8; j++) f[j] = px[j];
        } else {
#pragma unroll
            for (int j = 0; j < 8; j++) f[j] = make_float4(0.f, 0.f, 0.f, 0.f);
        }
#pragma unroll
        for (int g = 0; g < 4; g++) {
            uint4 st;
            st.x = pack2(f[2 * g].x, f[2 * g].y);
            st.y = pack2(f[2 * g].z, f[2 * g].w);
            st.z = pack2(f[2 * g + 1].x, f[2 * g + 1].y);
            st.w = pack2(f[2 * g + 1].z, f[2 * g + 1].w);
            *(uint4*)(As + r * 128 + ((k0 + 8 * g) ^ swz)) = st;
        }
    }
    bf16x8 bfrag[4][4];
#pragma unroll
    for (int n = 0; n < 4; n++) {
        int col = w * 64 + n * 16 + (l & 15);
        const u16* wrow = w1t + col * 128;
        int swz = (col & 7) << 3;
#pragma unroll
        for (int ks = 0; ks < 4; ks++)
            bfrag[n][ks] = *(const bf16x8*)(wrow + ((ks * 32 + (l >> 4) * 8) ^ swz));
    }
    __syncthreads();
    f32x4 z = {0.f, 0.f, 0.f, 0.f};
    f32x4 acc[4][4];
#pragma unroll
    for (int m = 0; m < 4; m++)
#pragma unroll
        for (int n = 0; n < 4; n++) acc[m][n] = z;
#pragma unroll
    for (int ks = 0; ks < 4; ks++) {
#pragma unroll
        for (int m = 0; m < 4; m++) {
            int row = m * 16 + (l & 15);
            bf16x8 a = *(const bf16x8*)(As + row * 128 +
                                        ((ks * 32 + (l >> 4) * 8) ^ ((row & 7) << 3)));
#pragma unroll
            for (int n = 0; n < 4; n++)
                acc[m][n] = __builtin_amdgcn_mfma_f32_16x16x32_bf16(a, bfrag[n][ks], acc[m][n], 0, 0, 0);
        }
    }
#pragma unroll
    for (int m = 0; m < 4; m++) {
        int rbase = r0 + m * 16 + (l >> 4) * 4;
#pragma unroll
        for (int n = 0; n < 4; n++) {
            int col = w * 64 + n * 16 + (l & 15);
#pragma unroll
            for (int r = 0; r < 4; r++) {
                int rr = rbase + r;
                if (rr < N) h1b[(size_t)rr * 256 + (col ^ ((rr & 7) << 3))] = f2bf(acc[m][n][r]);
            }
        }
    }
    // fused alpha1: per (m,r) the row lives in 16 lanes (same l>>4);
    // head of col n = w*8 + n*2 + ((l>>3)&1); reduce over 8 lanes.
    float as1v[4], ad1v[4];
#pragma unroll
    for (int n = 0; n < 4; n++) {
        int col = w * 64 + n * 16 + (l & 15);
        as1v[n] = as1[col];
        ad1v[n] = ad1[col];
    }
#pragma unroll
    for (int m = 0; m < 4; m++) {
#pragma unroll
        for (int r = 0; r < 4; r++) {
            int row = r0 + m * 16 + (l >> 4) * 4 + r;
#pragma unroll
            for (int n = 0; n < 4; n++) {
                float ps = acc[m][n][r] * as1v[n];
                float pd = acc[m][n][r] * ad1v[n];
#pragma unroll
                for (int o = 1; o < 8; o <<= 1) {
                    ps += __shfl_xor(ps, o, 64);
                    pd += __shfl_xor(pd, o, 64);
                }
                if ((l & 7) == 0 && row < N) {
                    int head = w * 8 + n * 2 + ((l >> 3) & 1);
                    asrc1[(size_t)row * H1 + head] = ps;
                    adst1[(size_t)row * H1 + head] = pd;
                }
            }
        }
    }
}

// ---------------------------------------------------------------------------
// 4. Edge pass 1: one wave per dst. Lane l: channels 4l..4l+3, head hl=l>>1.
//    csr index is wave-uniform -> readfirstlane -> SGPR addressing, no shuffles.
__global__ __launch_bounds__(256) void k_edge1(
        const int* __restrict__ rs, const int* __restrict__ csr,
        const u16* __restrict__ h1b, const float* __restrict__ asrc,
        const float* __restrict__ adst, const float* __restrict__ b1,
        u16* __restrict__ outb) {
    int d = blockIdx.x * 4 + (threadIdx.x >> 6);
    if (d >= N) return;
    int l = threadIdx.x & 63;
    int hl = l >> 1;
    int beg = rs[d], end = rs[d + 1];
    float ad_hl = adst[(size_t)d * H1 + hl];
    float wself = __expf(leaky(asrc[(size_t)d * H1 + hl] + ad_hl));
    float den = wself;
    int swzD = (d & 7) << 3;
    int ch4 = 4 * l;
    uint2 vd = *(const uint2*)(h1b + (size_t)d * 256 + (ch4 ^ swzD));
    float a0, a1, a2, a3;
    up2(vd.x, a0, a1); up2(vd.y, a2, a3);
    float c0 = wself * a0, c1 = wself * a1, c2 = wself * a2, c3 = wself * a3;

#pragma unroll 4
    for (int i = beg; i < end; ++i) {
        int s = __builtin_amdgcn_readfirstlane(csr[i]);
        float wv = __expf(leaky(asrc[(size_t)s * H1 + hl] + ad_hl));
        uint2 v = *(const uint2*)(h1b + (size_t)s * 256 + (ch4 ^ ((s & 7) << 3)));
        den += wv;
        float t0, t1, t2, t3;
        up2(v.x, t0, t1); up2(v.y, t2, t3);
        c0 = fmaf(wv, t0, c0); c1 = fmaf(wv, t1, c1);
        c2 = fmaf(wv, t2, c2); c3 = fmaf(wv, t3, c3);
    }
    float inv = 1.f / (den + 1e-16f);
    uint2 st;
    st.x = pack2(c0 * inv + b1[ch4], c1 * inv + b1[ch4 + 1]);
    st.y = pack2(c2 * inv + b1[ch4 + 2], c3 * inv + b1[ch4 + 3]);
    *(uint2*)(outb + (size_t)d * 256 + (ch4 ^ swzD)) = st;
}

// ---------------------------------------------------------------------------
// 5. GEMM2 (MFMA) + fused alpha2. Block 64 rows; wave w: rows w*16..+15.
__global__ __launch_bounds__(256) void k_gemm2(
        const u16* __restrict__ ab, const u16* __restrict__ w2t,
        const float* __restrict__ a2s, const float* __restrict__ a2d,
        u16* __restrict__ h2b, float* __restrict__ asrc2, float* __restrict__ adst2) {
    __shared__ u16 As[64 * 256];
    int r0 = blockIdx.x * 64;
    int t = threadIdx.x, w = t >> 6, l = t & 63;
    {
        const uint4* gsrc = (const uint4*)(ab + (size_t)r0 * 256);
        uint4* lds = (uint4*)As;
        for (int i = t; i < 2048; i += 256) lds[i] = gsrc[i];
    }
    __syncthreads();
    f32x4 z = {0.f, 0.f, 0.f, 0.f};
    f32x4 acc[4];
#pragma unroll
    for (int n = 0; n < 4; n++) acc[n] = z;
    int row = w * 16 + (l & 15);
    int swzA = (row & 7) << 3;
#pragma unroll
    for (int ks = 0; ks < 8; ks++) {
        int ka = ks * 32 + (l >> 4) * 8;
        bf16x8 a = *(const bf16x8*)(As + row * 256 + (ka ^ swzA));
#pragma unroll
        for (int n = 0; n < 4; n++) {
            int col = n * 16 + (l & 15);
            bf16x8 b = *(const bf16x8*)(w2t + col * 256 + (ka ^ ((col & 7) << 3)));
            acc[n] = __builtin_amdgcn_mfma_f32_16x16x32_bf16(a, b, acc[n], 0, 0, 0);
        }
    }
#pragma unroll
    for (int n = 0; n < 4; n++) {
        int col = n * 16 + (l & 15);
#pragma unroll
        for (int r = 0; r < 4; r++) {
            int rr = r0 + w * 16 + (l >> 4) * 4 + r;
            if (rr < N) h2b[(size_t)rr * F2 + col] = f2bf(acc[n][r]);
        }
    }
    // fused alpha2: full 64-col row lives in 16 lanes (same l>>4)
    float a2sv[4], a2dv[4];
#pragma unroll
    for (int n = 0; n < 4; n++) {
        a2sv[n] = a2s[n * 16 + (l & 15)];
        a2dv[n] = a2d[n * 16 + (l & 15)];
    }
#pragma unroll
    for (int r = 0; r < 4; r++) {
        int rr = r0 + w * 16 + (l >> 4) * 4 + r;
        float ps = 0.f, pd = 0.f;
#pragma unroll
        for (int n = 0; n < 4; n++) {
            ps = fmaf(acc[n][r], a2sv[n], ps);
            pd = fmaf(acc[n][r], a2dv[n], pd);
        }
#pragma unroll
        for (int o = 1; o < 16; o <<= 1) {
            ps += __shfl_xor(ps, o, 64);
            pd += __shfl_xor(pd, o, 64);
        }
        if ((l & 15) == 0 && rr < N) { asrc2[rr] = ps; adst2[rr] = pd; }
    }
}

// ---------------------------------------------------------------------------
// 6. Edge pass 2: one wave per node; lane l: quarter q=l>>4 (edge slot),
//    channels 4*(l&15)..+3. Per-lane direct csr loads, no shuffles in loop.
__global__ __launch_bounds__(256) void k_edge2(
        const int* __restrict__ rs, const int* __restrict__ csr,
        const u16* __restrict__ h2b, const float* __restrict__ asrc,
        const float* __restrict__ adst, const float* __restrict__ b2,
        float* __restrict__ out) {
    int d = blockIdx.x * 4 + (threadIdx.x >> 6);
    if (d >= N) return;
    int l = threadIdx.x & 63;
    int q = l >> 4, c4 = (l & 15) * 4;
    int beg = rs[d], end = rs[d + 1];
    float add_ = adst[d];
    float wself = __expf(leaky(asrc[d] + add_));
    float wq0 = (q == 0) ? wself : 0.f;
    float den = wq0;
    uint2 vd = *(const uint2*)(h2b + (size_t)d * F2 + c4);
    float a0, a1, a2, a3;
    up2(vd.x, a0, a1); up2(vd.y, a2, a3);
    float c0 = wq0 * a0, c1 = wq0 * a1, c2 = wq0 * a2, c3 = wq0 * a3;

    for (int i = beg + q; i < end; i += 4) {
        int s = csr[i];
        float wv = __expf(leaky(asrc[s] + add_));
        uint2 v = *(const uint2*)(h2b + (size_t)s * F2 + c4);
        den += wv;
        float t0, t1, t2, t3;
        up2(v.x, t0, t1); up2(v.y, t2, t3);
        c0 = fmaf(wv, t0, c0); c1 = fmaf(wv, t1, c1);
        c2 = fmaf(wv, t2, c2); c3 = fmaf(wv, t3, c3);
    }
    den += __shfl_xor(den, 16, 64); den += __shfl_xor(den, 32, 64);
    c0 += __shfl_xor(c0, 16, 64);   c0 += __shfl_xor(c0, 32, 64);
    c1 += __shfl_xor(c1, 16, 64);   c1 += __shfl_xor(c1, 32, 64);
    c2 += __shfl_xor(c2, 16, 64);   c2 += __shfl_xor(c2, 32, 64);
    c3 += __shfl_xor(c3, 16, 64);   c3 += __shfl_xor(c3, 32, 64);
    if (q == 0) {
        float inv = 1.f / (den + 1e-16f);
        float4 o;
        o.x = 1.f / (1.f + __expf(-(c0 * inv + b2[c4])));
        o.y = 1.f / (1.f + __expf(-(c1 * inv + b2[c4 + 1])));
        o.z = 1.f / (1.f + __expf(-(c2 * inv + b2[c4 + 2])));
        o.w = 1.f / (1.f + __expf(-(c3 * inv + b2[c4 + 3])));
        *(float4*)(out + (size_t)d * F2 + c4) = o;
    }
}

// ---------------------------------------------------------------------------
extern "C" void kernel_launch(void* const* d_in, const int* in_sizes, int n_in,
                              void* d_out, int out_size, void* d_ws, size_t ws_size,
                              hipStream_t stream) {
    const float* x   = (const float*)d_in[0];
    const void*  ei  = d_in[1];
    const float* W1  = (const float*)d_in[2];
    const float* as1 = (const float*)d_in[3];
    const float* ad1 = (const float*)d_in[4];
    const float* b1  = (const float*)d_in[5];
    const float* W2  = (const float*)d_in[6];
    const float* a2s = (const float*)d_in[7];
    const float* a2d = (const float*)d_in[8];
    const float* b2  = (const float*)d_in[9];
    float* out = (float*)d_out;

    char* wp = (char*)d_ws;
    size_t off = 0;
    auto alloc = [&](size_t bytes) {
        void* p = wp + off;
        off = (off + bytes + 255) & ~(size_t)255;
        return p;
    };
    int* flag  = (int*)alloc(4);
    int* deg   = (int*)alloc((size_t)N * 4);
    int* rs    = (int*)alloc((size_t)(N + 1) * 4);
    int* rs2   = (int*)alloc((size_t)N * 4);
    int* bsum  = (int*)alloc((size_t)NB * 4);
    int* csr   = (int*)alloc((size_t)E * 4);
    u16* w1t   = (u16*)alloc((size_t)W1SZ * 2);
    u16* w2t   = (u16*)alloc((size_t)W2SZ * 2);
    u16* h1b   = (u16*)alloc((size_t)NPAD * F1 * 2);
    u16* h1ab  = (u16*)alloc((size_t)NPAD * F1 * 2);
    u16* h2b   = (u16*)alloc((size_t)NPAD * F2 * 2);
    float* asrc1 = (float*)alloc((size_t)N * H1 * 4);
    float* adst1 = (float*)alloc((size_t)N * H1 * 4);
    float* asrc2 = (float*)alloc((size_t)N * 4);
    float* adst2 = (float*)alloc((size_t)N * 4);

    hipMemsetAsync(deg, 0, (size_t)N * 4, stream);

    k_detect<<<1, 1024, 0, stream>>>((const unsigned long long*)ei, flag);
    k_count<<<(E + 255) / 256, 256, 0, stream>>>(ei, flag, deg);
    k_bsum<<<NB, 256, 0, stream>>>(deg, bsum);
    k_bscan<<<1, 256, 0, stream>>>(bsum, rs + N);
    k_rs<<<NB, 256, 0, stream>>>(deg, bsum, rs);
    hipMemcpyAsync(rs2, rs, (size_t)N * 4, hipMemcpyDeviceToDevice, stream);
    k_scatter<<<(E + 255) / 256, 256, 0, stream>>>(ei, flag, rs2, csr);

    k_prepw<<<(W1SZ + W2SZ + 255) / 256, 256, 0, stream>>>(W1, W2, w1t, w2t);
    k_gemm1<<<NPAD / 64, 256, 0, stream>>>(x, w1t, as1, ad1, h1b, asrc1, adst1);
    k_edge1<<<(N + 3) / 4, 256, 0, stream>>>(rs, csr, h1b, asrc1, adst1, b1, h1ab);
    k_gemm2<<<NPAD / 64, 256, 0, stream>>>(h1ab, w2t, a2s, a2d, h2b, asrc2, adst2);
    k_edge2<<<(N + 3) / 4, 256, 0, stream>>>(rs, csr, h2b, asrc2, adst2, b2, out);
}

// Round 6
// 264.281 us; speedup vs baseline: 1.1200x; 1.1200x over previous
//
#include <hip/hip_runtime.h>
#include <hip/hip_bf16.h>

constexpr int N  = 50000;
constexpr int E  = 800000;
constexpr int F0 = 128;
constexpr int H1 = 32;
constexpr int F1 = 256;
constexpr int F2 = 64;
constexpr int NB = (N + 255) / 256;        // 196 scan blocks
constexpr int NPAD = 782 * 64;             // 50048
constexpr int W1SZ = F0 * F1;              // 32768
constexpr int W2SZ = F1 * F2;              // 16384
constexpr int VA1SZ = 64 * F0;             // 8192  (cols: 0-31 src heads, 32-63 dst heads)
constexpr int VA2SZ = 16 * F1;             // 4096  (rows 0/1 = src/dst, rest zero)
constexpr float NEG_SLOPE = 0.2f;

typedef unsigned short u16;
typedef unsigned int   u32;
typedef __attribute__((ext_vector_type(8))) short bf16x8;
typedef __attribute__((ext_vector_type(4))) float f32x4;

__device__ __forceinline__ float leaky(float e) {
    return fmaxf(e, 0.f) + NEG_SLOPE * fminf(e, 0.f);
}
__device__ __forceinline__ u16 f2bf(float f) {
    u32 u = __builtin_bit_cast(u32, f);
    u += 0x7fffu + ((u >> 16) & 1u);
    return (u16)(u >> 16);
}
__device__ __forceinline__ u32 pack2(float a, float b) {
    return (u32)f2bf(a) | ((u32)f2bf(b) << 16);
}
__device__ __forceinline__ void up2(u32 v, float& lo, float& hi) {
    lo = __builtin_bit_cast(float, v << 16);
    hi = __builtin_bit_cast(float, v & 0xffff0000u);
}

// in-wave edge_index dtype check: int64 data -> first 64 u64 all < N
__device__ __forceinline__ int is64_check(const void* ei) {
    const unsigned long long* p = (const unsigned long long*)ei;
    unsigned long long v = p[threadIdx.x & 63];
    return __all(v < (unsigned long long)N) ? 1 : 0;
}
__device__ __forceinline__ int load_idx(const void* ei, long long i, int is64) {
    return is64 ? (int)((const long long*)ei)[i] : ((const int*)ei)[i];
}

// ---------------------------------------------------------------------------
// 1. CSR build by dst
__global__ void k_count(const void* __restrict__ ei, int* __restrict__ deg) {
    int is64 = is64_check(ei);
    int e = blockIdx.x * blockDim.x + threadIdx.x;
    if (e >= E) return;
    int dst = load_idx(ei, (long long)E + e, is64);
    atomicAdd(&deg[dst], 1);
}
__global__ __launch_bounds__(256) void k_bsum(const int* __restrict__ deg, int* __restrict__ bsum) {
    int b = blockIdx.x, t = threadIdx.x, i = b * 256 + t;
    int v = (i < N) ? deg[i] : 0;
#pragma unroll
    for (int o = 1; o < 64; o <<= 1) v += __shfl_xor(v, o, 64);
    __shared__ int sw[4];
    if ((t & 63) == 0) sw[t >> 6] = v;
    __syncthreads();
    if (t == 0) bsum[b] = sw[0] + sw[1] + sw[2] + sw[3];
}
__global__ __launch_bounds__(256) void k_bscan(int* __restrict__ bsum, int* __restrict__ rsN) {
    int t = threadIdx.x, lane = t & 63, wy = t >> 6;
    int v = (t < NB) ? bsum[t] : 0;
    int inc = v;
#pragma unroll
    for (int o = 1; o < 64; o <<= 1) { int u = __shfl_up(inc, o, 64); if (lane >= o) inc += u; }
    __shared__ int wtot[4];
    if (lane == 63) wtot[wy] = inc;
    __syncthreads();
    int offs = 0;
    for (int k = 0; k < wy; k++) offs += wtot[k];
    int excl = offs + inc - v;
    if (t < NB) bsum[t] = excl;
    if (t == NB - 1) *rsN = excl + v;
}
__global__ __launch_bounds__(256) void k_rs(const int* __restrict__ deg,
                                            const int* __restrict__ bsum, int* __restrict__ rs) {
    int b = blockIdx.x, t = threadIdx.x, i = b * 256 + t;
    int lane = t & 63, wy = t >> 6;
    int v = (i < N) ? deg[i] : 0;
    int inc = v;
#pragma unroll
    for (int o = 1; o < 64; o <<= 1) { int u = __shfl_up(inc, o, 64); if (lane >= o) inc += u; }
    __shared__ int wtot[4];
    if (lane == 63) wtot[wy] = inc;
    __syncthreads();
    int offs = bsum[b];
    for (int k = 0; k < wy; k++) offs += wtot[k];
    if (i < N) rs[i] = offs + inc - v;
}
__global__ void k_scatter(const void* __restrict__ ei,
                          int* __restrict__ rs2, int* __restrict__ csr) {
    int is64 = is64_check(ei);
    int e = blockIdx.x * blockDim.x + threadIdx.x;
    if (e >= E) return;
    int src = load_idx(ei, e, is64);
    int dst = load_idx(ei, (long long)E + e, is64);
    int pos = atomicAdd(&rs2[dst], 1);
    csr[pos] = src;
}

// ---------------------------------------------------------------------------
// 2. Prep: weights fp32->bf16 transposed [n][k] pre-swizzled (k ^= (n&7)<<3),
//    plus folded attention matrices va1t [64][128], va2t [16][256].
__global__ __launch_bounds__(256) void k_prepw(
        const float* __restrict__ W1, const float* __restrict__ W2,
        const float* __restrict__ as1, const float* __restrict__ ad1,
        const float* __restrict__ a2s, const float* __restrict__ a2d,
        u16* __restrict__ w1t, u16* __restrict__ w2t,
        u16* __restrict__ va1t, u16* __restrict__ va2t) {
    int i = blockIdx.x * 256 + threadIdx.x;
    if (i < W1SZ) {
        int n = i >> 7, k = i & 127;
        w1t[(n << 7) + (k ^ ((n & 7) << 3))] = f2bf(W1[k * F1 + n]);
    } else if (i < W1SZ + W2SZ) {
        int j = i - W1SZ;
        int n = j >> 8, k = j & 255;
        w2t[(n << 8) + (k ^ ((n & 7) << 3))] = f2bf(W2[k * F2 + n]);
    } else if (i < W1SZ + W2SZ + VA1SZ) {
        int j = i - W1SZ - W2SZ;
        int c = j >> 7, k = j & 127;          // c: 0-31 src, 32-63 dst; head = c&31
        const float* a = (c < 32) ? as1 : ad1;
        int h = c & 31;
        float s = 0.f;
#pragma unroll
        for (int cc = 0; cc < 8; cc++) s += W1[k * F1 + h * 8 + cc] * a[h * 8 + cc];
        va1t[(c << 7) + (k ^ ((c & 7) << 3))] = f2bf(s);
    } else if (i < W1SZ + W2SZ + VA1SZ + VA2SZ) {
        int j = i - W1SZ - W2SZ - VA1SZ;
        int jj = j >> 8, k = j & 255;
        float s = 0.f;
        if (jj < 2) {
            const float* a = jj ? a2d : a2s;
            for (int c = 0; c < 64; c++) s += W2[k * F2 + c] * a[c];
        }
        va2t[(jj << 8) + (k ^ ((jj & 7) << 3))] = f2bf(s);
    }
}

// ---------------------------------------------------------------------------
// 3. GEMM1 (MFMA): h1 = x @ W1 (256 cols) + alpha cols (va1t) as 5th n-frag.
//    Block 64 rows, 4 waves; wave w: cols w*64..+63 plus alpha cols w*16..+15.
__global__ __launch_bounds__(256) void k_gemm1(
        const float* __restrict__ x, const u16* __restrict__ w1t,
        const u16* __restrict__ va1t, u16* __restrict__ h1b,
        float* __restrict__ asrc1, float* __restrict__ adst1) {
    __shared__ u16 As[64 * 128];   // 16KB, swizzled rows
    int r0 = blockIdx.x * 64;
    int t = threadIdx.x, w = t >> 6, l = t & 63;
    {   // stage: thread t -> row t>>2, 32 cols at (t&3)*32; fp32->bf16 inline
        int r = t >> 2, k0 = (t & 3) * 32, rr = r0 + r;
        int swz = (r & 7) << 3;
        float4 f[8];
        if (rr < N) {
            const float4* px = (const float4*)(x + (size_t)rr * F0 + k0);
#pragma unroll
            for (int j = 0; j < 8; j++) f[j] = px[j];
        } else {
#pragma unroll
            for (int j = 0; j < 8; j++) f[j] = make_float4(0.f, 0.f, 0.f, 0.f);
        }
#pragma unroll
        for (int g = 0; g < 4; g++) {
            uint4 st;
            st.x = pack2(f[2 * g].x, f[2 * g].y);
            st.y = pack2(f[2 * g].z, f[2 * g].w);
            st.z = pack2(f[2 * g + 1].x, f[2 * g + 1].y);
            st.w = pack2(f[2 * g + 1].z, f[2 * g + 1].w);
            *(uint4*)(As + r * 128 + ((k0 + 8 * g) ^ swz)) = st;
        }
    }
    bf16x8 bfrag[4][4];
#pragma unroll
    for (int n = 0; n < 4; n++) {
        int col = w * 64 + n * 16 + (l & 15);
        const u16* wrow = w1t + col * 128;
        int swz = (col & 7) << 3;
#pragma unroll
        for (int ks = 0; ks < 4; ks++)
            bfrag[n][ks] = *(const bf16x8*)(wrow + ((ks * 32 + (l >> 4) * 8) ^ swz));
    }
    __syncthreads();
    f32x4 z = {0.f, 0.f, 0.f, 0.f};
    f32x4 acc[4][4], acc5[4];
#pragma unroll
    for (int m = 0; m < 4; m++) {
        acc5[m] = z;
#pragma unroll
        for (int n = 0; n < 4; n++) acc[m][n] = z;
    }
    int c5 = w * 16 + (l & 15);               // alpha col 0..63
    const u16* varow = va1t + c5 * 128;
    int swz5 = (c5 & 7) << 3;
#pragma unroll
    for (int ks = 0; ks < 4; ks++) {
        bf16x8 b5 = *(const bf16x8*)(varow + ((ks * 32 + (l >> 4) * 8) ^ swz5));
#pragma unroll
        for (int m = 0; m < 4; m++) {
            int row = m * 16 + (l & 15);
            bf16x8 a = *(const bf16x8*)(As + row * 128 +
                                        ((ks * 32 + (l >> 4) * 8) ^ ((row & 7) << 3)));
#pragma unroll
            for (int n = 0; n < 4; n++)
                acc[m][n] = __builtin_amdgcn_mfma_f32_16x16x32_bf16(a, bfrag[n][ks], acc[m][n], 0, 0, 0);
            acc5[m] = __builtin_amdgcn_mfma_f32_16x16x32_bf16(a, b5, acc5[m], 0, 0, 0);
        }
    }
#pragma unroll
    for (int m = 0; m < 4; m++) {
        int rbase = r0 + m * 16 + (l >> 4) * 4;
#pragma unroll
        for (int n = 0; n < 4; n++) {
            int col = w * 64 + n * 16 + (l & 15);
#pragma unroll
            for (int r = 0; r < 4; r++) {
                int rr = rbase + r;
                if (rr < N) h1b[(size_t)rr * 256 + (col ^ ((rr & 7) << 3))] = f2bf(acc[m][n][r]);
            }
        }
        // alpha epilogue: direct store from C-fragment, no reduce
#pragma unroll
        for (int r = 0; r < 4; r++) {
            int rr = rbase + r;
            if (rr < N) {
                float v = acc5[m][r];
                if (c5 < 32) asrc1[(size_t)rr * H1 + c5] = v;
                else         adst1[(size_t)rr * H1 + (c5 - 32)] = v;
            }
        }
    }
}

// ---------------------------------------------------------------------------
// 4. Edge pass 1: one wave per dst. half=l>>5 picks edge A/B; h=l&31 is both
//    the head and the 16B slot (channels 8h..8h+7). No shuffles in the loop.
__global__ __launch_bounds__(256) void k_edge1(
        const int* __restrict__ rs, const int* __restrict__ csr,
        const u16* __restrict__ h1b, const float* __restrict__ asrc,
        const float* __restrict__ adst, const float* __restrict__ b1,
        u16* __restrict__ outb) {
    int d = blockIdx.x * 4 + (threadIdx.x >> 6);
    if (d >= N) return;
    int l = threadIdx.x & 63;
    int half = l >> 5, h = l & 31;
    int beg = rs[d], end = rs[d + 1];
    float adh = adst[(size_t)d * H1 + h];
    float wself = __expf(leaky(asrc[(size_t)d * H1 + h] + adh));
    float w0 = half ? 0.f : wself;
    float den = w0;
    float c0, c1, c2, c3, c4, c5, c6, c7;
    {
        uint4 vd = *(const uint4*)(h1b + (size_t)d * 256 + 8 * (h ^ (d & 7)));
        float t0, t1;
        up2(vd.x, t0, t1); c0 = w0 * t0; c1 = w0 * t1;
        up2(vd.y, t0, t1); c2 = w0 * t0; c3 = w0 * t1;
        up2(vd.z, t0, t1); c4 = w0 * t0; c5 = w0 * t1;
        up2(vd.w, t0, t1); c6 = w0 * t0; c7 = w0 * t1;
    }
#pragma unroll 2
    for (int i0 = beg; i0 < end; i0 += 2) {
        int i = i0 + half;
        bool ok = i < end;
        int s = ok ? csr[i] : d;
        float wv = ok ? __expf(leaky(asrc[(size_t)s * H1 + h] + adh)) : 0.f;
        uint4 v = *(const uint4*)(h1b + (size_t)s * 256 + 8 * (h ^ (s & 7)));
        den += wv;
        float t0, t1;
        up2(v.x, t0, t1); c0 = fmaf(wv, t0, c0); c1 = fmaf(wv, t1, c1);
        up2(v.y, t0, t1); c2 = fmaf(wv, t0, c2); c3 = fmaf(wv, t1, c3);
        up2(v.z, t0, t1); c4 = fmaf(wv, t0, c4); c5 = fmaf(wv, t1, c5);
        up2(v.w, t0, t1); c6 = fmaf(wv, t0, c6); c7 = fmaf(wv, t1, c7);
    }
    den += __shfl_xor(den, 32, 64);
    c0 += __shfl_xor(c0, 32, 64); c1 += __shfl_xor(c1, 32, 64);
    c2 += __shfl_xor(c2, 32, 64); c3 += __shfl_xor(c3, 32, 64);
    c4 += __shfl_xor(c4, 32, 64); c5 += __shfl_xor(c5, 32, 64);
    c6 += __shfl_xor(c6, 32, 64); c7 += __shfl_xor(c7, 32, 64);
    if (!half) {
        float inv = 1.f / (den + 1e-16f);
        int ch = 8 * h;
        uint4 st;
        st.x = pack2(c0 * inv + b1[ch],     c1 * inv + b1[ch + 1]);
        st.y = pack2(c2 * inv + b1[ch + 2], c3 * inv + b1[ch + 3]);
        st.z = pack2(c4 * inv + b1[ch + 4], c5 * inv + b1[ch + 5]);
        st.w = pack2(c6 * inv + b1[ch + 6], c7 * inv + b1[ch + 7]);
        *(uint4*)(outb + (size_t)d * 256 + 8 * (h ^ (d & 7))) = st;
    }
}

// ---------------------------------------------------------------------------
// 5. GEMM2 (MFMA): h2 = h1a @ W2 + alpha2 cols (va2t) as 5th n-frag.
__global__ __launch_bounds__(256) void k_gemm2(
        const u16* __restrict__ ab, const u16* __restrict__ w2t,
        const u16* __restrict__ va2t, u16* __restrict__ h2b,
        float* __restrict__ asrc2, float* __restrict__ adst2) {
    __shared__ u16 As[64 * 256];
    int r0 = blockIdx.x * 64;
    int t = threadIdx.x, w = t >> 6, l = t & 63;
    {
        const uint4* gsrc = (const uint4*)(ab + (size_t)r0 * 256);
        uint4* lds = (uint4*)As;
        for (int i = t; i < 2048; i += 256) lds[i] = gsrc[i];
    }
    __syncthreads();
    f32x4 z = {0.f, 0.f, 0.f, 0.f};
    f32x4 acc[4], acc5 = z;
#pragma unroll
    for (int n = 0; n < 4; n++) acc[n] = z;
    int row = w * 16 + (l & 15);
    int swzA = (row & 7) << 3;
    int j5 = l & 15;                          // va2t row; 0=src,1=dst
    int swz5 = (j5 & 7) << 3;
#pragma unroll
    for (int ks = 0; ks < 8; ks++) {
        int ka = ks * 32 + (l >> 4) * 8;
        bf16x8 a = *(const bf16x8*)(As + row * 256 + (ka ^ swzA));
#pragma unroll
        for (int n = 0; n < 4; n++) {
            int col = n * 16 + (l & 15);
            bf16x8 b = *(const bf16x8*)(w2t + col * 256 + (ka ^ ((col & 7) << 3)));
            acc[n] = __builtin_amdgcn_mfma_f32_16x16x32_bf16(a, b, acc[n], 0, 0, 0);
        }
        bf16x8 b5 = *(const bf16x8*)(va2t + j5 * 256 + (ka ^ swz5));
        acc5 = __builtin_amdgcn_mfma_f32_16x16x32_bf16(a, b5, acc5, 0, 0, 0);
    }
#pragma unroll
    for (int n = 0; n < 4; n++) {
        int col = n * 16 + (l & 15);
#pragma unroll
        for (int r = 0; r < 4; r++) {
            int rr = r0 + w * 16 + (l >> 4) * 4 + r;
            if (rr < N) h2b[(size_t)rr * F2 + col] = f2bf(acc[n][r]);
        }
    }
#pragma unroll
    for (int r = 0; r < 4; r++) {
        int rr = r0 + w * 16 + (l >> 4) * 4 + r;
        if (rr < N) {
            if (j5 == 0) asrc2[rr] = acc5[r];
            else if (j5 == 1) adst2[rr] = acc5[r];
        }
    }
}

// ---------------------------------------------------------------------------
// 6. Edge pass 2: one wave per node; 8 lanes per edge (q=l>>3), channels
//    8*(l&7)..+7 via uint4. No shuffles in loop; 3-level reduce at end.
__global__ __launch_bounds__(256) void k_edge2(
        const int* __restrict__ rs, const int* __restrict__ csr,
        const u16* __restrict__ h2b, const float* __restrict__ asrc,
        const float* __restrict__ adst, const float* __restrict__ b2,
        float* __restrict__ out) {
    int d = blockIdx.x * 4 + (threadIdx.x >> 6);
    if (d >= N) return;
    int l = threadIdx.x & 63;
    int q = l >> 3, c8 = (l & 7) * 8;
    int beg = rs[d], end = rs[d + 1];
    float add_ = adst[d];
    float wself = __expf(leaky(asrc[d] + add_));
    float w0 = (q == 0) ? wself : 0.f;
    float den = w0;
    float c0, c1, c2, c3, c4, c5, c6, c7;
    {
        uint4 vd = *(const uint4*)(h2b + (size_t)d * F2 + c8);
        float t0, t1;
        up2(vd.x, t0, t1); c0 = w0 * t0; c1 = w0 * t1;
        up2(vd.y, t0, t1); c2 = w0 * t0; c3 = w0 * t1;
        up2(vd.z, t0, t1); c4 = w0 * t0; c5 = w0 * t1;
        up2(vd.w, t0, t1); c6 = w0 * t0; c7 = w0 * t1;
    }
    for (int i0 = beg; i0 < end; i0 += 8) {
        int i = i0 + q;
        bool ok = i < end;
        int s = ok ? csr[i] : d;
        float wv = ok ? __expf(leaky(asrc[s] + add_)) : 0.f;
        uint4 v = *(const uint4*)(h2b + (size_t)s * F2 + c8);
        den += wv;
        float t0, t1;
        up2(v.x, t0, t1); c0 = fmaf(wv, t0, c0); c1 = fmaf(wv, t1, c1);
        up2(v.y, t0, t1); c2 = fmaf(wv, t0, c2); c3 = fmaf(wv, t1, c3);
        up2(v.z, t0, t1); c4 = fmaf(wv, t0, c4); c5 = fmaf(wv, t1, c5);
        up2(v.w, t0, t1); c6 = fmaf(wv, t0, c6); c7 = fmaf(wv, t1, c7);
    }
#pragma unroll
    for (int o = 8; o < 64; o <<= 1) {
        den += __shfl_xor(den, o, 64);
        c0 += __shfl_xor(c0, o, 64); c1 += __shfl_xor(c1, o, 64);
        c2 += __shfl_xor(c2, o, 64); c3 += __shfl_xor(c3, o, 64);
        c4 += __shfl_xor(c4, o, 64); c5 += __shfl_xor(c5, o, 64);
        c6 += __shfl_xor(c6, o, 64); c7 += __shfl_xor(c7, o, 64);
    }
    if (q == 0) {
        float inv = 1.f / (den + 1e-16f);
        float4 o1, o2;
        o1.x = 1.f / (1.f + __expf(-(c0 * inv + b2[c8])));
        o1.y = 1.f / (1.f + __expf(-(c1 * inv + b2[c8 + 1])));
        o1.z = 1.f / (1.f + __expf(-(c2 * inv + b2[c8 + 2])));
        o1.w = 1.f / (1.f + __expf(-(c3 * inv + b2[c8 + 3])));
        o2.x = 1.f / (1.f + __expf(-(c4 * inv + b2[c8 + 4])));
        o2.y = 1.f / (1.f + __expf(-(c5 * inv + b2[c8 + 5])));
        o2.z = 1.f / (1.f + __expf(-(c6 * inv + b2[c8 + 6])));
        o2.w = 1.f / (1.f + __expf(-(c7 * inv + b2[c8 + 7])));
        *(float4*)(out + (size_t)d * F2 + c8) = o1;
        *(float4*)(out + (size_t)d * F2 + c8 + 4) = o2;
    }
}

// ---------------------------------------------------------------------------
extern "C" void kernel_launch(void* const* d_in, const int* in_sizes, int n_in,
                              void* d_out, int out_size, void* d_ws, size_t ws_size,
                              hipStream_t stream) {
    const float* x   = (const float*)d_in[0];
    const void*  ei  = d_in[1];
    const float* W1  = (const float*)d_in[2];
    const float* as1 = (const float*)d_in[3];
    const float* ad1 = (const float*)d_in[4];
    const float* b1  = (const float*)d_in[5];
    const float* W2  = (const float*)d_in[6];
    const float* a2s = (const float*)d_in[7];
    const float* a2d = (const float*)d_in[8];
    const float* b2  = (const float*)d_in[9];
    float* out = (float*)d_out;

    char* wp = (char*)d_ws;
    size_t off = 0;
    auto alloc = [&](size_t bytes) {
        void* p = wp + off;
        off = (off + bytes + 255) & ~(size_t)255;
        return p;
    };
    int* deg   = (int*)alloc((size_t)N * 4);
    int* rs    = (int*)alloc((size_t)(N + 1) * 4);
    int* rs2   = (int*)alloc((size_t)N * 4);
    int* bsum  = (int*)alloc((size_t)NB * 4);
    int* csr   = (int*)alloc((size_t)E * 4);
    u16* w1t   = (u16*)alloc((size_t)W1SZ * 2);
    u16* w2t   = (u16*)alloc((size_t)W2SZ * 2);
    u16* va1t  = (u16*)alloc((size_t)VA1SZ * 2);
    u16* va2t  = (u16*)alloc((size_t)VA2SZ * 2);
    u16* h1b   = (u16*)alloc((size_t)NPAD * F1 * 2);
    u16* h1ab  = (u16*)alloc((size_t)NPAD * F1 * 2);
    u16* h2b   = (u16*)alloc((size_t)NPAD * F2 * 2);
    float* asrc1 = (float*)alloc((size_t)N * H1 * 4);
    float* adst1 = (float*)alloc((size_t)N * H1 * 4);
    float* asrc2 = (float*)alloc((size_t)N * 4);
    float* adst2 = (float*)alloc((size_t)N * 4);

    hipMemsetAsync(deg, 0, (size_t)N * 4, stream);

    k_count<<<(E + 255) / 256, 256, 0, stream>>>(ei, deg);
    k_bsum<<<NB, 256, 0, stream>>>(deg, bsum);
    k_bscan<<<1, 256, 0, stream>>>(bsum, rs + N);
    k_rs<<<NB, 256, 0, stream>>>(deg, bsum, rs);
    hipMemcpyAsync(rs2, rs, (size_t)N * 4, hipMemcpyDeviceToDevice, stream);
    k_scatter<<<(E + 255) / 256, 256, 0, stream>>>(ei, rs2, csr);

    k_prepw<<<(W1SZ + W2SZ + VA1SZ + VA2SZ + 255) / 256, 256, 0, stream>>>(
        W1, W2, as1, ad1, a2s, a2d, w1t, w2t, va1t, va2t);
    k_gemm1<<<NPAD / 64, 256, 0, stream>>>(x, w1t, va1t, h1b, asrc1, adst1);
    k_edge1<<<(N + 3) / 4, 256, 0, stream>>>(rs, csr, h1b, asrc1, adst1, b1, h1ab);
    k_gemm2<<<NPAD / 64, 256, 0, stream>>>(h1ab, w2t, va2t, h2b, asrc2, adst2);
    k_edge2<<<(N + 3) / 4, 256, 0, stream>>>(rs, csr, h2b, asrc2, adst2, b2, out);
}

// Round 7
// 248.731 us; speedup vs baseline: 1.1901x; 1.0625x over previous
//
#include <hip/hip_runtime.h>
#include <hip/hip_bf16.h>

constexpr int N  = 50000;
constexpr int E  = 800000;
constexpr int F0 = 128;
constexpr int H1 = 32;
constexpr int F1 = 256;
constexpr int F2 = 64;
constexpr int NB = (N + 255) / 256;        // 196 scan blocks
constexpr int NPAD = 782 * 64;             // 50048
constexpr int W1SZ = F0 * F1;              // 32768
constexpr int W2SZ = F1 * F2;              // 16384
constexpr int VA1SZ = 64 * F0;             // 8192  (cols: 0-31 src heads, 32-63 dst heads)
constexpr int VA2SZ = 16 * F1;             // 4096  (rows 0/1 = src/dst, rest zero)
constexpr float NEG_SLOPE = 0.2f;

typedef unsigned short u16;
typedef unsigned int   u32;
typedef __attribute__((ext_vector_type(8))) short bf16x8;
typedef __attribute__((ext_vector_type(4))) float f32x4;

__device__ __forceinline__ float leaky(float e) {
    return fmaxf(e, 0.f) + NEG_SLOPE * fminf(e, 0.f);
}
__device__ __forceinline__ u16 f2bf(float f) {
    u32 u = __builtin_bit_cast(u32, f);
    u += 0x7fffu + ((u >> 16) & 1u);
    return (u16)(u >> 16);
}
__device__ __forceinline__ u32 pack2(float a, float b) {
    return (u32)f2bf(a) | ((u32)f2bf(b) << 16);
}
__device__ __forceinline__ void up2(u32 v, float& lo, float& hi) {
    lo = __builtin_bit_cast(float, v << 16);
    hi = __builtin_bit_cast(float, v & 0xffff0000u);
}

// in-wave edge_index dtype check: int64 data -> first 64 u64 all < N
__device__ __forceinline__ int is64_check(const void* ei) {
    const unsigned long long* p = (const unsigned long long*)ei;
    unsigned long long v = p[threadIdx.x & 63];
    return __all(v < (unsigned long long)N) ? 1 : 0;
}
__device__ __forceinline__ int load_idx(const void* ei, long long i, int is64) {
    return is64 ? (int)((const long long*)ei)[i] : ((const int*)ei)[i];
}

// ---------------------------------------------------------------------------
// 1. CSR build by dst
__global__ void k_count(const void* __restrict__ ei, int* __restrict__ deg) {
    int is64 = is64_check(ei);
    int e = blockIdx.x * blockDim.x + threadIdx.x;
    if (e >= E) return;
    int dst = load_idx(ei, (long long)E + e, is64);
    atomicAdd(&deg[dst], 1);
}
__global__ __launch_bounds__(256) void k_bsum(const int* __restrict__ deg, int* __restrict__ bsum) {
    int b = blockIdx.x, t = threadIdx.x, i = b * 256 + t;
    int v = (i < N) ? deg[i] : 0;
#pragma unroll
    for (int o = 1; o < 64; o <<= 1) v += __shfl_xor(v, o, 64);
    __shared__ int sw[4];
    if ((t & 63) == 0) sw[t >> 6] = v;
    __syncthreads();
    if (t == 0) bsum[b] = sw[0] + sw[1] + sw[2] + sw[3];
}
__global__ __launch_bounds__(256) void k_bscan(int* __restrict__ bsum, int* __restrict__ rsN) {
    int t = threadIdx.x, lane = t & 63, wy = t >> 6;
    int v = (t < NB) ? bsum[t] : 0;
    int inc = v;
#pragma unroll
    for (int o = 1; o < 64; o <<= 1) { int u = __shfl_up(inc, o, 64); if (lane >= o) inc += u; }
    __shared__ int wtot[4];
    if (lane == 63) wtot[wy] = inc;
    __syncthreads();
    int offs = 0;
    for (int k = 0; k < wy; k++) offs += wtot[k];
    int excl = offs + inc - v;
    if (t < NB) bsum[t] = excl;
    if (t == NB - 1) *rsN = excl + v;
}
__global__ __launch_bounds__(256) void k_rs(const int* __restrict__ deg,
                                            const int* __restrict__ bsum, int* __restrict__ rs) {
    int b = blockIdx.x, t = threadIdx.x, i = b * 256 + t;
    int lane = t & 63, wy = t >> 6;
    int v = (i < N) ? deg[i] : 0;
    int inc = v;
#pragma unroll
    for (int o = 1; o < 64; o <<= 1) { int u = __shfl_up(inc, o, 64); if (lane >= o) inc += u; }
    __shared__ int wtot[4];
    if (lane == 63) wtot[wy] = inc;
    __syncthreads();
    int offs = bsum[b];
    for (int k = 0; k < wy; k++) offs += wtot[k];
    if (i < N) rs[i] = offs + inc - v;
}
__global__ void k_scatter(const void* __restrict__ ei,
                          int* __restrict__ rs2, int* __restrict__ csr) {
    int is64 = is64_check(ei);
    int e = blockIdx.x * blockDim.x + threadIdx.x;
    if (e >= E) return;
    int src = load_idx(ei, e, is64);
    int dst = load_idx(ei, (long long)E + e, is64);
    int pos = atomicAdd(&rs2[dst], 1);
    csr[pos] = src;
}

// ---------------------------------------------------------------------------
// 2. Prep: weights fp32->bf16 transposed [n][k] pre-swizzled (k ^= (n&7)<<3),
//    plus folded attention matrices va1t [64][128], va2t [16][256].
__global__ __launch_bounds__(256) void k_prepw(
        const float* __restrict__ W1, const float* __restrict__ W2,
        const float* __restrict__ as1, const float* __restrict__ ad1,
        const float* __restrict__ a2s, const float* __restrict__ a2d,
        u16* __restrict__ w1t, u16* __restrict__ w2t,
        u16* __restrict__ va1t, u16* __restrict__ va2t) {
    int i = blockIdx.x * 256 + threadIdx.x;
    if (i < W1SZ) {
        int n = i >> 7, k = i & 127;
        w1t[(n << 7) + (k ^ ((n & 7) << 3))] = f2bf(W1[k * F1 + n]);
    } else if (i < W1SZ + W2SZ) {
        int j = i - W1SZ;
        int n = j >> 8, k = j & 255;
        w2t[(n << 8) + (k ^ ((n & 7) << 3))] = f2bf(W2[k * F2 + n]);
    } else if (i < W1SZ + W2SZ + VA1SZ) {
        int j = i - W1SZ - W2SZ;
        int c = j >> 7, k = j & 127;          // c: 0-31 src, 32-63 dst; head = c&31
        const float* a = (c < 32) ? as1 : ad1;
        int h = c & 31;
        float s = 0.f;
#pragma unroll
        for (int cc = 0; cc < 8; cc++) s += W1[k * F1 + h * 8 + cc] * a[h * 8 + cc];
        va1t[(c << 7) + (k ^ ((c & 7) << 3))] = f2bf(s);
    } else if (i < W1SZ + W2SZ + VA1SZ + VA2SZ) {
        int j = i - W1SZ - W2SZ - VA1SZ;
        int jj = j >> 8, k = j & 255;
        float s = 0.f;
        if (jj < 2) {
            const float* a = jj ? a2d : a2s;
            for (int c = 0; c < 64; c++) s += W2[k * F2 + c] * a[c];
        }
        va2t[(jj << 8) + (k ^ ((jj & 7) << 3))] = f2bf(s);
    }
}

// ---------------------------------------------------------------------------
// 3. GEMM1 (MFMA): h1 = x @ W1 (256 cols) + alpha cols (va1t) as 5th n-frag.
__global__ __launch_bounds__(256) void k_gemm1(
        const float* __restrict__ x, const u16* __restrict__ w1t,
        const u16* __restrict__ va1t, u16* __restrict__ h1b,
        float* __restrict__ asrc1, float* __restrict__ adst1) {
    __shared__ u16 As[64 * 128];   // 16KB, swizzled rows
    int r0 = blockIdx.x * 64;
    int t = threadIdx.x, w = t >> 6, l = t & 63;
    {   // stage: thread t -> row t>>2, 32 cols at (t&3)*32; fp32->bf16 inline
        int r = t >> 2, k0 = (t & 3) * 32, rr = r0 + r;
        int swz = (r & 7) << 3;
        float4 f[8];
        if (rr < N) {
            const float4* px = (const float4*)(x + (size_t)rr * F0 + k0);
#pragma unroll
            for (int j = 0; j < 8; j++) f[j] = px[j];
        } else {
#pragma unroll
            for (int j = 0; j < 8; j++) f[j] = make_float4(0.f, 0.f, 0.f, 0.f);
        }
#pragma unroll
        for (int g = 0; g < 4; g++) {
            uint4 st;
            st.x = pack2(f[2 * g].x, f[2 * g].y);
            st.y = pack2(f[2 * g].z, f[2 * g].w);
            st.z = pack2(f[2 * g + 1].x, f[2 * g + 1].y);
            st.w = pack2(f[2 * g + 1].z, f[2 * g + 1].w);
            *(uint4*)(As + r * 128 + ((k0 + 8 * g) ^ swz)) = st;
        }
    }
    bf16x8 bfrag[4][4];
#pragma unroll
    for (int n = 0; n < 4; n++) {
        int col = w * 64 + n * 16 + (l & 15);
        const u16* wrow = w1t + col * 128;
        int swz = (col & 7) << 3;
#pragma unroll
        for (int ks = 0; ks < 4; ks++)
            bfrag[n][ks] = *(const bf16x8*)(wrow + ((ks * 32 + (l >> 4) * 8) ^ swz));
    }
    __syncthreads();
    f32x4 z = {0.f, 0.f, 0.f, 0.f};
    f32x4 acc[4][4], acc5[4];
#pragma unroll
    for (int m = 0; m < 4; m++) {
        acc5[m] = z;
#pragma unroll
        for (int n = 0; n < 4; n++) acc[m][n] = z;
    }
    int c5 = w * 16 + (l & 15);               // alpha col 0..63
    const u16* varow = va1t + c5 * 128;
    int swz5 = (c5 & 7) << 3;
#pragma unroll
    for (int ks = 0; ks < 4; ks++) {
        bf16x8 b5 = *(const bf16x8*)(varow + ((ks * 32 + (l >> 4) * 8) ^ swz5));
#pragma unroll
        for (int m = 0; m < 4; m++) {
            int row = m * 16 + (l & 15);
            bf16x8 a = *(const bf16x8*)(As + row * 128 +
                                        ((ks * 32 + (l >> 4) * 8) ^ ((row & 7) << 3)));
#pragma unroll
            for (int n = 0; n < 4; n++)
                acc[m][n] = __builtin_amdgcn_mfma_f32_16x16x32_bf16(a, bfrag[n][ks], acc[m][n], 0, 0, 0);
            acc5[m] = __builtin_amdgcn_mfma_f32_16x16x32_bf16(a, b5, acc5[m], 0, 0, 0);
        }
    }
#pragma unroll
    for (int m = 0; m < 4; m++) {
        int rbase = r0 + m * 16 + (l >> 4) * 4;
#pragma unroll
        for (int n = 0; n < 4; n++) {
            int col = w * 64 + n * 16 + (l & 15);
#pragma unroll
            for (int r = 0; r < 4; r++) {
                int rr = rbase + r;
                if (rr < N) h1b[(size_t)rr * 256 + (col ^ ((rr & 7) << 3))] = f2bf(acc[m][n][r]);
            }
        }
#pragma unroll
        for (int r = 0; r < 4; r++) {
            int rr = rbase + r;
            if (rr < N) {
                float v = acc5[m][r];
                if (c5 < 32) asrc1[(size_t)rr * H1 + c5] = v;
                else         adst1[(size_t)rr * H1 + (c5 - 32)] = v;
            }
        }
    }
}

// ---------------------------------------------------------------------------
// 4. Edge pass 1: one wave per dst; half=l>>5 picks edge slot, h=l&31 is head
//    AND 16B channel-slot. Batch of 16 edges (8 per half): 3 unrolled phases
//    (csr loads -> asrc+h1b loads -> consume) = 16 outstanding row-gathers.
__global__ __launch_bounds__(256) void k_edge1(
        const int* __restrict__ rs, const int* __restrict__ csr,
        const u16* __restrict__ h1b, const float* __restrict__ asrc,
        const float* __restrict__ adst, const float* __restrict__ b1,
        u16* __restrict__ outb) {
    int d = blockIdx.x * 4 + (threadIdx.x >> 6);
    if (d >= N) return;
    int l = threadIdx.x & 63;
    int half = l >> 5, h = l & 31;
    int beg = rs[d], end = rs[d + 1];
    float adh = adst[(size_t)d * H1 + h];
    float wself = __expf(leaky(asrc[(size_t)d * H1 + h] + adh));
    float w0 = half ? 0.f : wself;
    float den = w0;
    float c0, c1, c2, c3, c4, c5, c6, c7;
    {
        uint4 vd = *(const uint4*)(h1b + (size_t)d * 256 + 8 * (h ^ (d & 7)));
        float t0, t1;
        up2(vd.x, t0, t1); c0 = w0 * t0; c1 = w0 * t1;
        up2(vd.y, t0, t1); c2 = w0 * t0; c3 = w0 * t1;
        up2(vd.z, t0, t1); c4 = w0 * t0; c5 = w0 * t1;
        up2(vd.w, t0, t1); c6 = w0 * t0; c7 = w0 * t1;
    }
    const uint4 z4 = {0u, 0u, 0u, 0u};
    for (int i0 = beg; i0 < end; i0 += 16) {
        int   s[8];
        float av[8];
        uint4 v[8];
#pragma unroll
        for (int k = 0; k < 8; k++) {
            int i = i0 + 2 * k + half;
            s[k] = (i < end) ? csr[i] : -1;
        }
#pragma unroll
        for (int k = 0; k < 8; k++) {
            av[k] = 0.f; v[k] = z4;
            if (s[k] >= 0) {
                av[k] = asrc[(size_t)s[k] * H1 + h];
                v[k] = *(const uint4*)(h1b + (size_t)s[k] * 256 + 8 * (h ^ (s[k] & 7)));
            }
        }
#pragma unroll
        for (int k = 0; k < 8; k++) {
            float wv = (s[k] >= 0) ? __expf(leaky(av[k] + adh)) : 0.f;
            den += wv;
            float t0, t1;
            up2(v[k].x, t0, t1); c0 = fmaf(wv, t0, c0); c1 = fmaf(wv, t1, c1);
            up2(v[k].y, t0, t1); c2 = fmaf(wv, t0, c2); c3 = fmaf(wv, t1, c3);
            up2(v[k].z, t0, t1); c4 = fmaf(wv, t0, c4); c5 = fmaf(wv, t1, c5);
            up2(v[k].w, t0, t1); c6 = fmaf(wv, t0, c6); c7 = fmaf(wv, t1, c7);
        }
    }
    den += __shfl_xor(den, 32, 64);
    c0 += __shfl_xor(c0, 32, 64); c1 += __shfl_xor(c1, 32, 64);
    c2 += __shfl_xor(c2, 32, 64); c3 += __shfl_xor(c3, 32, 64);
    c4 += __shfl_xor(c4, 32, 64); c5 += __shfl_xor(c5, 32, 64);
    c6 += __shfl_xor(c6, 32, 64); c7 += __shfl_xor(c7, 32, 64);
    if (!half) {
        float inv = 1.f / (den + 1e-16f);
        int ch = 8 * h;
        uint4 st;
        st.x = pack2(c0 * inv + b1[ch],     c1 * inv + b1[ch + 1]);
        st.y = pack2(c2 * inv + b1[ch + 2], c3 * inv + b1[ch + 3]);
        st.z = pack2(c4 * inv + b1[ch + 4], c5 * inv + b1[ch + 5]);
        st.w = pack2(c6 * inv + b1[ch + 6], c7 * inv + b1[ch + 7]);
        *(uint4*)(outb + (size_t)d * 256 + 8 * (h ^ (d & 7))) = st;
    }
}

// ---------------------------------------------------------------------------
// 5. GEMM2 (MFMA): h2 = h1a @ W2 + alpha2 cols (va2t) as 5th n-frag.
__global__ __launch_bounds__(256) void k_gemm2(
        const u16* __restrict__ ab, const u16* __restrict__ w2t,
        const u16* __restrict__ va2t, u16* __restrict__ h2b,
        float* __restrict__ asrc2, float* __restrict__ adst2) {
    __shared__ u16 As[64 * 256];
    int r0 = blockIdx.x * 64;
    int t = threadIdx.x, w = t >> 6, l = t & 63;
    {
        const uint4* gsrc = (const uint4*)(ab + (size_t)r0 * 256);
        uint4* lds = (uint4*)As;
        for (int i = t; i < 2048; i += 256) lds[i] = gsrc[i];
    }
    __syncthreads();
    f32x4 z = {0.f, 0.f, 0.f, 0.f};
    f32x4 acc[4], acc5 = z;
#pragma unroll
    for (int n = 0; n < 4; n++) acc[n] = z;
    int row = w * 16 + (l & 15);
    int swzA = (row & 7) << 3;
    int j5 = l & 15;                          // va2t row; 0=src,1=dst
    int swz5 = (j5 & 7) << 3;
#pragma unroll
    for (int ks = 0; ks < 8; ks++) {
        int ka = ks * 32 + (l >> 4) * 8;
        bf16x8 a = *(const bf16x8*)(As + row * 256 + (ka ^ swzA));
#pragma unroll
        for (int n = 0; n < 4; n++) {
            int col = n * 16 + (l & 15);
            bf16x8 b = *(const bf16x8*)(w2t + col * 256 + (ka ^ ((col & 7) << 3)));
            acc[n] = __builtin_amdgcn_mfma_f32_16x16x32_bf16(a, b, acc[n], 0, 0, 0);
        }
        bf16x8 b5 = *(const bf16x8*)(va2t + j5 * 256 + (ka ^ swz5));
        acc5 = __builtin_amdgcn_mfma_f32_16x16x32_bf16(a, b5, acc5, 0, 0, 0);
    }
#pragma unroll
    for (int n = 0; n < 4; n++) {
        int col = n * 16 + (l & 15);
#pragma unroll
        for (int r = 0; r < 4; r++) {
            int rr = r0 + w * 16 + (l >> 4) * 4 + r;
            if (rr < N) h2b[(size_t)rr * F2 + col] = f2bf(acc[n][r]);
        }
    }
#pragma unroll
    for (int r = 0; r < 4; r++) {
        int rr = r0 + w * 16 + (l >> 4) * 4 + r;
        if (rr < N) {
            if (j5 == 0) asrc2[rr] = acc5[r];
            else if (j5 == 1) adst2[rr] = acc5[r];
        }
    }
}

// ---------------------------------------------------------------------------
// 6. Edge pass 2: one wave per node; 8 lanes per edge (q=l>>3), channels
//    8*(l&7)..+7 via uint4; batch 2 -> 16 edges in flight.
__global__ __launch_bounds__(256) void k_edge2(
        const int* __restrict__ rs, const int* __restrict__ csr,
        const u16* __restrict__ h2b, const float* __restrict__ asrc,
        const float* __restrict__ adst, const float* __restrict__ b2,
        float* __restrict__ out) {
    int d = blockIdx.x * 4 + (threadIdx.x >> 6);
    if (d >= N) return;
    int l = threadIdx.x & 63;
    int q = l >> 3, c8 = (l & 7) * 8;
    int beg = rs[d], end = rs[d + 1];
    float add_ = adst[d];
    float wself = __expf(leaky(asrc[d] + add_));
    float w0 = (q == 0) ? wself : 0.f;
    float den = w0;
    float c0, c1, c2, c3, c4, c5, c6, c7;
    {
        uint4 vd = *(const uint4*)(h2b + (size_t)d * F2 + c8);
        float t0, t1;
        up2(vd.x, t0, t1); c0 = w0 * t0; c1 = w0 * t1;
        up2(vd.y, t0, t1); c2 = w0 * t0; c3 = w0 * t1;
        up2(vd.z, t0, t1); c4 = w0 * t0; c5 = w0 * t1;
        up2(vd.w, t0, t1); c6 = w0 * t0; c7 = w0 * t1;
    }
    const uint4 z4 = {0u, 0u, 0u, 0u};
    for (int i0 = beg; i0 < end; i0 += 16) {
        int   s[2];
        float av[2];
        uint4 v[2];
#pragma unroll
        for (int k = 0; k < 2; k++) {
            int i = i0 + 8 * k + q;
            s[k] = (i < end) ? csr[i] : -1;
        }
#pragma unroll
        for (int k = 0; k < 2; k++) {
            av[k] = 0.f; v[k] = z4;
            if (s[k] >= 0) {
                av[k] = asrc[s[k]];
                v[k] = *(const uint4*)(h2b + (size_t)s[k] * F2 + c8);
            }
        }
#pragma unroll
        for (int k = 0; k < 2; k++) {
            float wv = (s[k] >= 0) ? __expf(leaky(av[k] + add_)) : 0.f;
            den += wv;
            float t0, t1;
            up2(v[k].x, t0, t1); c0 = fmaf(wv, t0, c0); c1 = fmaf(wv, t1, c1);
            up2(v[k].y, t0, t1); c2 = fmaf(wv, t0, c2); c3 = fmaf(wv, t1, c3);
            up2(v[k].z, t0, t1); c4 = fmaf(wv, t0, c4); c5 = fmaf(wv, t1, c5);
            up2(v[k].w, t0, t1); c6 = fmaf(wv, t0, c6); c7 = fmaf(wv, t1, c7);
        }
    }
#pragma unroll
    for (int o = 8; o < 64; o <<= 1) {
        den += __shfl_xor(den, o, 64);
        c0 += __shfl_xor(c0, o, 64); c1 += __shfl_xor(c1, o, 64);
        c2 += __shfl_xor(c2, o, 64); c3 += __shfl_xor(c3, o, 64);
        c4 += __shfl_xor(c4, o, 64); c5 += __shfl_xor(c5, o, 64);
        c6 += __shfl_xor(c6, o, 64); c7 += __shfl_xor(c7, o, 64);
    }
    if (q == 0) {
        float inv = 1.f / (den + 1e-16f);
        float4 o1, o2;
        o1.x = 1.f / (1.f + __expf(-(c0 * inv + b2[c8])));
        o1.y = 1.f / (1.f + __expf(-(c1 * inv + b2[c8 + 1])));
        o1.z = 1.f / (1.f + __expf(-(c2 * inv + b2[c8 + 2])));
        o1.w = 1.f / (1.f + __expf(-(c3 * inv + b2[c8 + 3])));
        o2.x = 1.f / (1.f + __expf(-(c4 * inv + b2[c8 + 4])));
        o2.y = 1.f / (1.f + __expf(-(c5 * inv + b2[c8 + 5])));
        o2.z = 1.f / (1.f + __expf(-(c6 * inv + b2[c8 + 6])));
        o2.w = 1.f / (1.f + __expf(-(c7 * inv + b2[c8 + 7])));
        *(float4*)(out + (size_t)d * F2 + c8) = o1;
        *(float4*)(out + (size_t)d * F2 + c8 + 4) = o2;
    }
}

// ---------------------------------------------------------------------------
extern "C" void kernel_launch(void* const* d_in, const int* in_sizes, int n_in,
                              void* d_out, int out_size, void* d_ws, size_t ws_size,
                              hipStream_t stream) {
    const float* x   = (const float*)d_in[0];
    const void*  ei  = d_in[1];
    const float* W1  = (const float*)d_in[2];
    const float* as1 = (const float*)d_in[3];
    const float* ad1 = (const float*)d_in[4];
    const float* b1  = (const float*)d_in[5];
    const float* W2  = (const float*)d_in[6];
    const float* a2s = (const float*)d_in[7];
    const float* a2d = (const float*)d_in[8];
    const float* b2  = (const float*)d_in[9];
    float* out = (float*)d_out;

    char* wp = (char*)d_ws;
    size_t off = 0;
    auto alloc = [&](size_t bytes) {
        void* p = wp + off;
        off = (off + bytes + 255) & ~(size_t)255;
        return p;
    };
    int* deg   = (int*)alloc((size_t)N * 4);
    int* rs    = (int*)alloc((size_t)(N + 1) * 4);
    int* rs2   = (int*)alloc((size_t)N * 4);
    int* bsum  = (int*)alloc((size_t)NB * 4);
    int* csr   = (int*)alloc((size_t)E * 4);
    u16* w1t   = (u16*)alloc((size_t)W1SZ * 2);
    u16* w2t   = (u16*)alloc((size_t)W2SZ * 2);
    u16* va1t  = (u16*)alloc((size_t)VA1SZ * 2);
    u16* va2t  = (u16*)alloc((size_t)VA2SZ * 2);
    u16* h1b   = (u16*)alloc((size_t)NPAD * F1 * 2);
    u16* h1ab  = (u16*)alloc((size_t)NPAD * F1 * 2);
    u16* h2b   = (u16*)alloc((size_t)NPAD * F2 * 2);
    float* asrc1 = (float*)alloc((size_t)N * H1 * 4);
    float* adst1 = (float*)alloc((size_t)N * H1 * 4);
    float* asrc2 = (float*)alloc((size_t)N * 4);
    float* adst2 = (float*)alloc((size_t)N * 4);

    hipMemsetAsync(deg, 0, (size_t)N * 4, stream);

    k_count<<<(E + 255) / 256, 256, 0, stream>>>(ei, deg);
    k_bsum<<<NB, 256, 0, stream>>>(deg, bsum);
    k_bscan<<<1, 256, 0, stream>>>(bsum, rs + N);
    k_rs<<<NB, 256, 0, stream>>>(deg, bsum, rs);
    hipMemcpyAsync(rs2, rs, (size_t)N * 4, hipMemcpyDeviceToDevice, stream);
    k_scatter<<<(E + 255) / 256, 256, 0, stream>>>(ei, rs2, csr);

    k_prepw<<<(W1SZ + W2SZ + VA1SZ + VA2SZ + 255) / 256, 256, 0, stream>>>(
        W1, W2, as1, ad1, a2s, a2d, w1t, w2t, va1t, va2t);
    k_gemm1<<<NPAD / 64, 256, 0, stream>>>(x, w1t, va1t, h1b, asrc1, adst1);
    k_edge1<<<(N + 3) / 4, 256, 0, stream>>>(rs, csr, h1b, asrc1, adst1, b1, h1ab);
    k_gemm2<<<NPAD / 64, 256, 0, stream>>>(h1ab, w2t, va2t, h2b, asrc2, adst2);
    k_edge2<<<(N + 3) / 4, 256, 0, stream>>>(rs, csr, h2b, asrc2, adst2, b2, out);
}

// Round 8
// 231.426 us; speedup vs baseline: 1.2790x; 1.0748x over previous
//
#include <hip/hip_runtime.h>
#include <hip/hip_bf16.h>

constexpr int N  = 50000;
constexpr int E  = 800000;
constexpr int F0 = 128;
constexpr int H1 = 32;
constexpr int F1 = 256;
constexpr int F2 = 64;
constexpr int NB = (N + 255) / 256;        // 196 scan blocks
constexpr int NPAD = 782 * 64;             // 50048
constexpr int W1SZ = F0 * F1;              // 32768
constexpr int W2SZ = F1 * F2;              // 16384
constexpr int VA1SZ = 64 * F0;             // 8192
constexpr int VA2SZ = 16 * F1;             // 4096
constexpr int PREPB = (W1SZ + W2SZ + VA1SZ + VA2SZ) / 256;  // 240
constexpr int INITB = PREPB + NB;          // 436
constexpr int GB1 = NPAD / 64;             // 782 gemm1 blocks
constexpr int CB  = (E + 255) / 256;       // 3125 count blocks
constexpr float NEG_SLOPE = 0.2f;

typedef unsigned short u16;
typedef unsigned int   u32;
typedef __attribute__((ext_vector_type(8))) short bf16x8;
typedef __attribute__((ext_vector_type(4))) float f32x4;
typedef __attribute__((ext_vector_type(2))) float f32x2;

__device__ __forceinline__ float leaky(float e) {
    return fmaxf(e, 0.f) + NEG_SLOPE * fminf(e, 0.f);
}
__device__ __forceinline__ float bf2f(u16 u) {
    u32 v = ((u32)u) << 16;
    return __builtin_bit_cast(float, v);
}
__device__ __forceinline__ u16 f2bf(float f) {
    u32 u = __builtin_bit_cast(u32, f);
    u += 0x7fffu + ((u >> 16) & 1u);
    return (u16)(u >> 16);
}
__device__ __forceinline__ u32 pack2(float a, float b) {
    return (u32)f2bf(a) | ((u32)f2bf(b) << 16);
}
__device__ __forceinline__ void up2(u32 v, float& lo, float& hi) {
    lo = __builtin_bit_cast(float, v << 16);
    hi = __builtin_bit_cast(float, v & 0xffff0000u);
}
__device__ __forceinline__ f32x2 up2v(u32 v) {
    f32x2 r;
    r.x = __builtin_bit_cast(float, v << 16);
    r.y = __builtin_bit_cast(float, v & 0xffff0000u);
    return r;
}

// in-wave edge_index dtype check: int64 data -> first 64 u64 all < N
__device__ __forceinline__ int is64_check(const void* ei) {
    const unsigned long long* p = (const unsigned long long*)ei;
    unsigned long long v = p[threadIdx.x & 63];
    return __all(v < (unsigned long long)N) ? 1 : 0;
}
__device__ __forceinline__ int load_idx(const void* ei, long long i, int is64) {
    return is64 ? (int)((const long long*)ei)[i] : ((const int*)ei)[i];
}

// ---------------------------------------------------------------------------
// 0. init: prep weights (fp32->bf16, [n][k] transposed, pre-swizzled) +
//    folded attention cols, AND zero deg. One dispatch.
__global__ __launch_bounds__(256) void k_init(
        const float* __restrict__ W1, const float* __restrict__ W2,
        const float* __restrict__ as1, const float* __restrict__ ad1,
        const float* __restrict__ a2s, const float* __restrict__ a2d,
        u16* __restrict__ w1t, u16* __restrict__ w2t,
        u16* __restrict__ va1t, u16* __restrict__ va2t, int* __restrict__ deg) {
    int b = blockIdx.x;
    if (b >= PREPB) {
        int i = (b - PREPB) * 256 + threadIdx.x;
        if (i < N) deg[i] = 0;
        return;
    }
    int i = b * 256 + threadIdx.x;
    if (i < W1SZ) {
        int n = i >> 7, k = i & 127;
        w1t[(n << 7) + (k ^ ((n & 7) << 3))] = f2bf(W1[k * F1 + n]);
    } else if (i < W1SZ + W2SZ) {
        int j = i - W1SZ;
        int n = j >> 8, k = j & 255;
        w2t[(n << 8) + (k ^ ((n & 7) << 3))] = f2bf(W2[k * F2 + n]);
    } else if (i < W1SZ + W2SZ + VA1SZ) {
        int j = i - W1SZ - W2SZ;
        int c = j >> 7, k = j & 127;          // c: 0-31 src, 32-63 dst
        const float* a = (c < 32) ? as1 : ad1;
        int h = c & 31;
        float s = 0.f;
#pragma unroll
        for (int cc = 0; cc < 8; cc++) s += W1[k * F1 + h * 8 + cc] * a[h * 8 + cc];
        va1t[(c << 7) + (k ^ ((c & 7) << 3))] = f2bf(s);
    } else if (i < W1SZ + W2SZ + VA1SZ + VA2SZ) {
        int j = i - W1SZ - W2SZ - VA1SZ;
        int jj = j >> 8, k = j & 255;
        float s = 0.f;
        if (jj < 2) {
            const float* a = jj ? a2d : a2s;
            for (int c = 0; c < 64; c++) s += W2[k * F2 + c] * a[c];
        }
        va2t[(jj << 8) + (k ^ ((jj & 7) << 3))] = f2bf(s);
    }
}

// ---------------------------------------------------------------------------
// 1. Fused GEMM1 (MFMA, blocks < GB1) + edge count (blocks >= GB1).
//    GEMM1: h1 = x @ W1 + alpha cols (va1t); alpha1 stored bf16.
__global__ __launch_bounds__(256) void k_gemm1count(
        const float* __restrict__ x, const u16* __restrict__ w1t,
        const u16* __restrict__ va1t, u16* __restrict__ h1b,
        u16* __restrict__ asrc1b, u16* __restrict__ adst1b,
        const void* __restrict__ ei, int* __restrict__ deg) {
    if (blockIdx.x >= GB1) {
        int is64 = is64_check(ei);
        int e = (blockIdx.x - GB1) * 256 + threadIdx.x;
        if (e < E) {
            int dst = load_idx(ei, (long long)E + e, is64);
            atomicAdd(&deg[dst], 1);
        }
        return;
    }
    __shared__ u16 As[64 * 128];   // 16KB, swizzled rows
    int r0 = blockIdx.x * 64;
    int t = threadIdx.x, w = t >> 6, l = t & 63;
    {   // stage: thread t -> row t>>2, 32 cols at (t&3)*32; fp32->bf16 inline
        int r = t >> 2, k0 = (t & 3) * 32, rr = r0 + r;
        int swz = (r & 7) << 3;
        float4 f[8];
        if (rr < N) {
            const float4* px = (const float4*)(x + (size_t)rr * F0 + k0);
#pragma unroll
            for (int j = 0; j < 8; j++) f[j] = px[j];
        } else {
#pragma unroll
            for (int j = 0; j < 8; j++) f[j] = make_float4(0.f, 0.f, 0.f, 0.f);
        }
#pragma unroll
        for (int g = 0; g < 4; g++) {
            uint4 st;
            st.x = pack2(f[2 * g].x, f[2 * g].y);
            st.y = pack2(f[2 * g].z, f[2 * g].w);
            st.z = pack2(f[2 * g + 1].x, f[2 * g + 1].y);
            st.w = pack2(f[2 * g + 1].z, f[2 * g + 1].w);
            *(uint4*)(As + r * 128 + ((k0 + 8 * g) ^ swz)) = st;
        }
    }
    bf16x8 bfrag[4][4];
#pragma unroll
    for (int n = 0; n < 4; n++) {
        int col = w * 64 + n * 16 + (l & 15);
        const u16* wrow = w1t + col * 128;
        int swz = (col & 7) << 3;
#pragma unroll
        for (int ks = 0; ks < 4; ks++)
            bfrag[n][ks] = *(const bf16x8*)(wrow + ((ks * 32 + (l >> 4) * 8) ^ swz));
    }
    __syncthreads();
    f32x4 z = {0.f, 0.f, 0.f, 0.f};
    f32x4 acc[4][4], acc5[4];
#pragma unroll
    for (int m = 0; m < 4; m++) {
        acc5[m] = z;
#pragma unroll
        for (int n = 0; n < 4; n++) acc[m][n] = z;
    }
    int c5 = w * 16 + (l & 15);               // alpha col 0..63
    const u16* varow = va1t + c5 * 128;
    int swz5 = (c5 & 7) << 3;
#pragma unroll
    for (int ks = 0; ks < 4; ks++) {
        bf16x8 b5 = *(const bf16x8*)(varow + ((ks * 32 + (l >> 4) * 8) ^ swz5));
#pragma unroll
        for (int m = 0; m < 4; m++) {
            int row = m * 16 + (l & 15);
            bf16x8 a = *(const bf16x8*)(As + row * 128 +
                                        ((ks * 32 + (l >> 4) * 8) ^ ((row & 7) << 3)));
#pragma unroll
            for (int n = 0; n < 4; n++)
                acc[m][n] = __builtin_amdgcn_mfma_f32_16x16x32_bf16(a, bfrag[n][ks], acc[m][n], 0, 0, 0);
            acc5[m] = __builtin_amdgcn_mfma_f32_16x16x32_bf16(a, b5, acc5[m], 0, 0, 0);
        }
    }
#pragma unroll
    for (int m = 0; m < 4; m++) {
        int rbase = r0 + m * 16 + (l >> 4) * 4;
#pragma unroll
        for (int n = 0; n < 4; n++) {
            int col = w * 64 + n * 16 + (l & 15);
#pragma unroll
            for (int r = 0; r < 4; r++) {
                int rr = rbase + r;
                if (rr < N) h1b[(size_t)rr * 256 + (col ^ ((rr & 7) << 3))] = f2bf(acc[m][n][r]);
            }
        }
#pragma unroll
        for (int r = 0; r < 4; r++) {
            int rr = rbase + r;
            if (rr < N) {
                u16 v = f2bf(acc5[m][r]);
                if (c5 < 32) asrc1b[(size_t)rr * H1 + c5] = v;
                else         adst1b[(size_t)rr * H1 + (c5 - 32)] = v;
            }
        }
    }
}

// ---------------------------------------------------------------------------
// 2. Scan chain (3 small kernels); k_rs also writes the scatter cursor rs2.
__global__ __launch_bounds__(256) void k_bsum(const int* __restrict__ deg, int* __restrict__ bsum) {
    int b = blockIdx.x, t = threadIdx.x, i = b * 256 + t;
    int v = (i < N) ? deg[i] : 0;
#pragma unroll
    for (int o = 1; o < 64; o <<= 1) v += __shfl_xor(v, o, 64);
    __shared__ int sw[4];
    if ((t & 63) == 0) sw[t >> 6] = v;
    __syncthreads();
    if (t == 0) bsum[b] = sw[0] + sw[1] + sw[2] + sw[3];
}
__global__ __launch_bounds__(256) void k_bscan(int* __restrict__ bsum, int* __restrict__ rsN) {
    int t = threadIdx.x, lane = t & 63, wy = t >> 6;
    int v = (t < NB) ? bsum[t] : 0;
    int inc = v;
#pragma unroll
    for (int o = 1; o < 64; o <<= 1) { int u = __shfl_up(inc, o, 64); if (lane >= o) inc += u; }
    __shared__ int wtot[4];
    if (lane == 63) wtot[wy] = inc;
    __syncthreads();
    int offs = 0;
    for (int k = 0; k < wy; k++) offs += wtot[k];
    int excl = offs + inc - v;
    if (t < NB) bsum[t] = excl;
    if (t == NB - 1) *rsN = excl + v;
}
__global__ __launch_bounds__(256) void k_rs(const int* __restrict__ deg,
                                            const int* __restrict__ bsum,
                                            int* __restrict__ rs, int* __restrict__ rs2) {
    int b = blockIdx.x, t = threadIdx.x, i = b * 256 + t;
    int lane = t & 63, wy = t >> 6;
    int v = (i < N) ? deg[i] : 0;
    int inc = v;
#pragma unroll
    for (int o = 1; o < 64; o <<= 1) { int u = __shfl_up(inc, o, 64); if (lane >= o) inc += u; }
    __shared__ int wtot[4];
    if (lane == 63) wtot[wy] = inc;
    __syncthreads();
    int offs = bsum[b];
    for (int k = 0; k < wy; k++) offs += wtot[k];
    if (i < N) {
        int e = offs + inc - v;
        rs[i] = e;
        rs2[i] = e;
    }
}
__global__ void k_scatter(const void* __restrict__ ei,
                          int* __restrict__ rs2, int* __restrict__ csr) {
    int is64 = is64_check(ei);
    int e = blockIdx.x * blockDim.x + threadIdx.x;
    if (e >= E) return;
    int src = load_idx(ei, e, is64);
    int dst = load_idx(ei, (long long)E + e, is64);
    int pos = atomicAdd(&rs2[dst], 1);
    csr[pos] = src;
}

// ---------------------------------------------------------------------------
// 3. Edge pass 1: one wave per dst; half=l>>5 edge slot, h=l&31 head+16B slot.
//    Batch 16 edges (8/half), 3 unrolled phases; bf16 alpha; f32x2 pk-fma.
__global__ __launch_bounds__(256) void k_edge1(
        const int* __restrict__ rs, const int* __restrict__ csr,
        const u16* __restrict__ h1b, const u16* __restrict__ asrcb,
        const u16* __restrict__ adstb, const float* __restrict__ b1,
        u16* __restrict__ outb) {
    int d = blockIdx.x * 4 + (threadIdx.x >> 6);
    if (d >= N) return;
    int l = threadIdx.x & 63;
    int half = l >> 5, h = l & 31;
    int beg = rs[d], end = rs[d + 1];
    float adh = bf2f(adstb[(size_t)d * H1 + h]);
    float wself = __expf(leaky(bf2f(asrcb[(size_t)d * H1 + h]) + adh));
    float w0 = half ? 0.f : wself;
    float den = w0;
    f32x2 c0, c1, c2, c3;
    {
        uint4 vd = *(const uint4*)(h1b + (size_t)d * 256 + 8 * (h ^ (d & 7)));
        c0 = up2v(vd.x) * w0;
        c1 = up2v(vd.y) * w0;
        c2 = up2v(vd.z) * w0;
        c3 = up2v(vd.w) * w0;
    }
    const uint4 z4 = {0u, 0u, 0u, 0u};
    for (int i0 = beg; i0 < end; i0 += 16) {
        int s[8]; u16 avu[8]; uint4 v[8];
#pragma unroll
        for (int k = 0; k < 8; k++) {
            int i = i0 + 2 * k + half;
            s[k] = (i < end) ? csr[i] : -1;
        }
#pragma unroll
        for (int k = 0; k < 8; k++) {
            avu[k] = 0; v[k] = z4;
            if (s[k] >= 0) {
                avu[k] = asrcb[(size_t)s[k] * H1 + h];
                v[k] = *(const uint4*)(h1b + (size_t)s[k] * 256 + 8 * (h ^ (s[k] & 7)));
            }
        }
#pragma unroll
        for (int k = 0; k < 8; k++) {
            float wv = (s[k] >= 0) ? __expf(leaky(bf2f(avu[k]) + adh)) : 0.f;
            den += wv;
            f32x2 w2v = {wv, wv};
            c0 = __builtin_elementwise_fma(up2v(v[k].x), w2v, c0);
            c1 = __builtin_elementwise_fma(up2v(v[k].y), w2v, c1);
            c2 = __builtin_elementwise_fma(up2v(v[k].z), w2v, c2);
            c3 = __builtin_elementwise_fma(up2v(v[k].w), w2v, c3);
        }
    }
    den += __shfl_xor(den, 32, 64);
    c0.x += __shfl_xor(c0.x, 32, 64); c0.y += __shfl_xor(c0.y, 32, 64);
    c1.x += __shfl_xor(c1.x, 32, 64); c1.y += __shfl_xor(c1.y, 32, 64);
    c2.x += __shfl_xor(c2.x, 32, 64); c2.y += __shfl_xor(c2.y, 32, 64);
    c3.x += __shfl_xor(c3.x, 32, 64); c3.y += __shfl_xor(c3.y, 32, 64);
    if (!half) {
        float inv = 1.f / (den + 1e-16f);
        int ch = 8 * h;
        uint4 st;
        st.x = pack2(c0.x * inv + b1[ch],     c0.y * inv + b1[ch + 1]);
        st.y = pack2(c1.x * inv + b1[ch + 2], c1.y * inv + b1[ch + 3]);
        st.z = pack2(c2.x * inv + b1[ch + 4], c2.y * inv + b1[ch + 5]);
        st.w = pack2(c3.x * inv + b1[ch + 6], c3.y * inv + b1[ch + 7]);
        *(uint4*)(outb + (size_t)d * 256 + 8 * (h ^ (d & 7))) = st;
    }
}

// ---------------------------------------------------------------------------
// 4. GEMM2 (MFMA): h2 = h1a @ W2 + alpha2 cols (va2t) as 5th n-frag.
__global__ __launch_bounds__(256) void k_gemm2(
        const u16* __restrict__ ab, const u16* __restrict__ w2t,
        const u16* __restrict__ va2t, u16* __restrict__ h2b,
        float* __restrict__ asrc2, float* __restrict__ adst2) {
    __shared__ u16 As[64 * 256];
    int r0 = blockIdx.x * 64;
    int t = threadIdx.x, w = t >> 6, l = t & 63;
    {
        const uint4* gsrc = (const uint4*)(ab + (size_t)r0 * 256);
        uint4* lds = (uint4*)As;
        for (int i = t; i < 2048; i += 256) lds[i] = gsrc[i];
    }
    __syncthreads();
    f32x4 z = {0.f, 0.f, 0.f, 0.f};
    f32x4 acc[4], acc5 = z;
#pragma unroll
    for (int n = 0; n < 4; n++) acc[n] = z;
    int row = w * 16 + (l & 15);
    int swzA = (row & 7) << 3;
    int j5 = l & 15;                          // va2t row; 0=src,1=dst
    int swz5 = (j5 & 7) << 3;
#pragma unroll
    for (int ks = 0; ks < 8; ks++) {
        int ka = ks * 32 + (l >> 4) * 8;
        bf16x8 a = *(const bf16x8*)(As + row * 256 + (ka ^ swzA));
#pragma unroll
        for (int n = 0; n < 4; n++) {
            int col = n * 16 + (l & 15);
            bf16x8 b = *(const bf16x8*)(w2t + col * 256 + (ka ^ ((col & 7) << 3)));
            acc[n] = __builtin_amdgcn_mfma_f32_16x16x32_bf16(a, b, acc[n], 0, 0, 0);
        }
        bf16x8 b5 = *(const bf16x8*)(va2t + j5 * 256 + (ka ^ swz5));
        acc5 = __builtin_amdgcn_mfma_f32_16x16x32_bf16(a, b5, acc5, 0, 0, 0);
    }
#pragma unroll
    for (int n = 0; n < 4; n++) {
        int col = n * 16 + (l & 15);
#pragma unroll
        for (int r = 0; r < 4; r++) {
            int rr = r0 + w * 16 + (l >> 4) * 4 + r;
            if (rr < N) h2b[(size_t)rr * F2 + col] = f2bf(acc[n][r]);
        }
    }
#pragma unroll
    for (int r = 0; r < 4; r++) {
        int rr = r0 + w * 16 + (l >> 4) * 4 + r;
        if (rr < N) {
            if (j5 == 0) asrc2[rr] = acc5[r];
            else if (j5 == 1) adst2[rr] = acc5[r];
        }
    }
}

// ---------------------------------------------------------------------------
// 5. Edge pass 2: one wave per node; 8 lanes/edge (q=l>>3); batch 2; f32x2.
__global__ __launch_bounds__(256) void k_edge2(
        const int* __restrict__ rs, const int* __restrict__ csr,
        const u16* __restrict__ h2b, const float* __restrict__ asrc,
        const float* __restrict__ adst, const float* __restrict__ b2,
        float* __restrict__ out) {
    int d = blockIdx.x * 4 + (threadIdx.x >> 6);
    if (d >= N) return;
    int l = threadIdx.x & 63;
    int q = l >> 3, c8 = (l & 7) * 8;
    int beg = rs[d], end = rs[d + 1];
    float add_ = adst[d];
    float wself = __expf(leaky(asrc[d] + add_));
    float w0 = (q == 0) ? wself : 0.f;
    float den = w0;
    f32x2 c0, c1, c2, c3;
    {
        uint4 vd = *(const uint4*)(h2b + (size_t)d * F2 + c8);
        c0 = up2v(vd.x) * w0;
        c1 = up2v(vd.y) * w0;
        c2 = up2v(vd.z) * w0;
        c3 = up2v(vd.w) * w0;
    }
    const uint4 z4 = {0u, 0u, 0u, 0u};
    for (int i0 = beg; i0 < end; i0 += 16) {
        int s[2]; float av[2]; uint4 v[2];
#pragma unroll
        for (int k = 0; k < 2; k++) {
            int i = i0 + 8 * k + q;
            s[k] = (i < end) ? csr[i] : -1;
        }
#pragma unroll
        for (int k = 0; k < 2; k++) {
            av[k] = 0.f; v[k] = z4;
            if (s[k] >= 0) {
                av[k] = asrc[s[k]];
                v[k] = *(const uint4*)(h2b + (size_t)s[k] * F2 + c8);
            }
        }
#pragma unroll
        for (int k = 0; k < 2; k++) {
            float wv = (s[k] >= 0) ? __expf(leaky(av[k] + add_)) : 0.f;
            den += wv;
            f32x2 w2v = {wv, wv};
            c0 = __builtin_elementwise_fma(up2v(v[k].x), w2v, c0);
            c1 = __builtin_elementwise_fma(up2v(v[k].y), w2v, c1);
            c2 = __builtin_elementwise_fma(up2v(v[k].z), w2v, c2);
            c3 = __builtin_elementwise_fma(up2v(v[k].w), w2v, c3);
        }
    }
#pragma unroll
    for (int o = 8; o < 64; o <<= 1) {
        den += __shfl_xor(den, o, 64);
        c0.x += __shfl_xor(c0.x, o, 64); c0.y += __shfl_xor(c0.y, o, 64);
        c1.x += __shfl_xor(c1.x, o, 64); c1.y += __shfl_xor(c1.y, o, 64);
        c2.x += __shfl_xor(c2.x, o, 64); c2.y += __shfl_xor(c2.y, o, 64);
        c3.x += __shfl_xor(c3.x, o, 64); c3.y += __shfl_xor(c3.y, o, 64);
    }
    if (q == 0) {
        float inv = 1.f / (den + 1e-16f);
        float4 o1, o2;
        o1.x = 1.f / (1.f + __expf(-(c0.x * inv + b2[c8])));
        o1.y = 1.f / (1.f + __expf(-(c0.y * inv + b2[c8 + 1])));
        o1.z = 1.f / (1.f + __expf(-(c1.x * inv + b2[c8 + 2])));
        o1.w = 1.f / (1.f + __expf(-(c1.y * inv + b2[c8 + 3])));
        o2.x = 1.f / (1.f + __expf(-(c2.x * inv + b2[c8 + 4])));
        o2.y = 1.f / (1.f + __expf(-(c2.y * inv + b2[c8 + 5])));
        o2.z = 1.f / (1.f + __expf(-(c3.x * inv + b2[c8 + 6])));
        o2.w = 1.f / (1.f + __expf(-(c3.y * inv + b2[c8 + 7])));
        *(float4*)(out + (size_t)d * F2 + c8) = o1;
        *(float4*)(out + (size_t)d * F2 + c8 + 4) = o2;
    }
}

// ---------------------------------------------------------------------------
extern "C" void kernel_launch(void* const* d_in, const int* in_sizes, int n_in,
                              void* d_out, int out_size, void* d_ws, size_t ws_size,
                              hipStream_t stream) {
    const float* x   = (const float*)d_in[0];
    const void*  ei  = d_in[1];
    const float* W1  = (const float*)d_in[2];
    const float* as1 = (const float*)d_in[3];
    const float* ad1 = (const float*)d_in[4];
    const float* b1  = (const float*)d_in[5];
    const float* W2  = (const float*)d_in[6];
    const float* a2s = (const float*)d_in[7];
    const float* a2d = (const float*)d_in[8];
    const float* b2  = (const float*)d_in[9];
    float* out = (float*)d_out;

    char* wp = (char*)d_ws;
    size_t off = 0;
    auto alloc = [&](size_t bytes) {
        void* p = wp + off;
        off = (off + bytes + 255) & ~(size_t)255;
        return p;
    };
    int* deg   = (int*)alloc((size_t)N * 4);
    int* rs    = (int*)alloc((size_t)(N + 1) * 4);
    int* rs2   = (int*)alloc((size_t)N * 4);
    int* bsum  = (int*)alloc((size_t)NB * 4);
    int* csr   = (int*)alloc((size_t)E * 4);
    u16* w1t   = (u16*)alloc((size_t)W1SZ * 2);
    u16* w2t   = (u16*)alloc((size_t)W2SZ * 2);
    u16* va1t  = (u16*)alloc((size_t)VA1SZ * 2);
    u16* va2t  = (u16*)alloc((size_t)VA2SZ * 2);
    u16* h1b   = (u16*)alloc((size_t)NPAD * F1 * 2);
    u16* h1ab  = (u16*)alloc((size_t)NPAD * F1 * 2);
    u16* h2b   = (u16*)alloc((size_t)NPAD * F2 * 2);
    u16* asrc1b = (u16*)alloc((size_t)N * H1 * 2);
    u16* adst1b = (u16*)alloc((size_t)N * H1 * 2);
    float* asrc2 = (float*)alloc((size_t)N * 4);
    float* adst2 = (float*)alloc((size_t)N * 4);

    k_init<<<INITB, 256, 0, stream>>>(W1, W2, as1, ad1, a2s, a2d,
                                      w1t, w2t, va1t, va2t, deg);
    k_gemm1count<<<GB1 + CB, 256, 0, stream>>>(x, w1t, va1t, h1b,
                                               asrc1b, adst1b, ei, deg);
    k_bsum<<<NB, 256, 0, stream>>>(deg, bsum);
    k_bscan<<<1, 256, 0, stream>>>(bsum, rs + N);
    k_rs<<<NB, 256, 0, stream>>>(deg, bsum, rs, rs2);
    k_scatter<<<CB, 256, 0, stream>>>(ei, rs2, csr);
    k_edge1<<<(N + 3) / 4, 256, 0, stream>>>(rs, csr, h1b, asrc1b, adst1b, b1, h1ab);
    k_gemm2<<<GB1, 256, 0, stream>>>(h1ab, w2t, va2t, h2b, asrc2, adst2);
    k_edge2<<<(N + 3) / 4, 256, 0, stream>>>(rs, csr, h2b, asrc2, adst2, b2, out);
}